// Round 1
// baseline (693.768 us; speedup 1.0000x reference)
//
#include <hip/hip_runtime.h>

// UniGCNConv2: X[vertex] --mean-seg-by-edges--> Xe *dege --gather+seg-sum-by-vertex--> Xv *degv
// --L2 row normalize--> @ W + b
//
// Sizes: N=100000 nodes, M=200000 edges, E=1e6 pairs, D_IN=64, out 128.

#define DIN 64
#define DOUT 128

// K2: scatter X rows into per-edge sums. One wave (64 lanes) per incidence pair.
__global__ __launch_bounds__(256) void k_scatter_ve(
    const float* __restrict__ X, const int* __restrict__ vertex,
    const int* __restrict__ edges, float* __restrict__ sums,
    float* __restrict__ counts, int E) {
  long long gid = (long long)blockIdx.x * blockDim.x + threadIdx.x;
  int pair = (int)(gid >> 6);
  int lane = (int)(gid & 63);
  if (pair >= E) return;
  int v = vertex[pair];
  int e = edges[pair];
  float val = X[(size_t)v * DIN + lane];
  atomicAdd(&sums[(size_t)e * DIN + lane], val);
  if (lane == 0) atomicAdd(&counts[e], 1.0f);
}

// K3: sums -> Xe in place: sums[e][d] * dege[e] / max(count[e],1)
__global__ __launch_bounds__(256) void k_edge_scale(
    float* __restrict__ sums, const float* __restrict__ counts,
    const float* __restrict__ dege, int M) {
  int i = blockIdx.x * blockDim.x + threadIdx.x;
  if (i >= M * DIN) return;
  int e = i >> 6;  // DIN == 64
  float c = counts[e];
  float s = dege[e] / fmaxf(c, 1.0f);
  sums[i] *= s;
}

// K4: scatter Xe rows back into per-node sums Xv.
__global__ __launch_bounds__(256) void k_scatter_ev(
    const float* __restrict__ Xe, const int* __restrict__ vertex,
    const int* __restrict__ edges, float* __restrict__ xv, int E) {
  long long gid = (long long)blockIdx.x * blockDim.x + threadIdx.x;
  int pair = (int)(gid >> 6);
  int lane = (int)(gid & 63);
  if (pair >= E) return;
  int v = vertex[pair];
  int e = edges[pair];
  float val = Xe[(size_t)e * DIN + lane];
  atomicAdd(&xv[(size_t)v * DIN + lane], val);
}

// K5: per node (one wave each): *degv, L2 normalize, @W + b.
__global__ __launch_bounds__(256) void k_final(
    const float* __restrict__ xv, const float* __restrict__ degv,
    const float* __restrict__ W, const float* __restrict__ b,
    float* __restrict__ out, int N) {
  __shared__ float Ws[DIN * DOUT];  // 32 KB
  for (int i = threadIdx.x; i < DIN * DOUT; i += blockDim.x) Ws[i] = W[i];
  __syncthreads();

  long long gid = (long long)blockIdx.x * blockDim.x + threadIdx.x;
  int node = (int)(gid >> 6);
  int lane = (int)(gid & 63);
  if (node >= N) return;

  float x = xv[(size_t)node * DIN + lane] * degv[node];
  // sum of squares across the 64-lane wave
  float ss = x * x;
  #pragma unroll
  for (int o = 32; o > 0; o >>= 1) ss += __shfl_xor(ss, o);
  float nrm = sqrtf(ss);
  float scale = nrm > 0.0f ? 1.0f / nrm : 0.0f;
  float xn = x * scale;

  float acc0 = b[lane];
  float acc1 = b[lane + 64];
  #pragma unroll
  for (int k = 0; k < DIN; ++k) {
    float xk = __shfl(xn, k);
    acc0 += xk * Ws[k * DOUT + lane];
    acc1 += xk * Ws[k * DOUT + 64 + lane];
  }
  out[(size_t)node * DOUT + lane] = acc0;
  out[(size_t)node * DOUT + 64 + lane] = acc1;
}

extern "C" void kernel_launch(void* const* d_in, const int* in_sizes, int n_in,
                              void* d_out, int out_size, void* d_ws, size_t ws_size,
                              hipStream_t stream) {
  const float* X      = (const float*)d_in[0];
  const int*   vertex = (const int*)d_in[1];
  const int*   edges  = (const int*)d_in[2];
  const float* dege   = (const float*)d_in[3];
  const float* degv   = (const float*)d_in[4];
  const float* W      = (const float*)d_in[5];
  const float* b      = (const float*)d_in[6];
  float* out = (float*)d_out;

  int N = in_sizes[0] / DIN;   // 100000
  int E = in_sizes[1];         // 1000000
  int M = in_sizes[3];         // 200000

  // workspace layout: sums[M*64] | counts[M] | xv[N*64]
  float* sums   = (float*)d_ws;
  float* counts = sums + (size_t)M * DIN;
  float* xv     = counts + (size_t)M;
  size_t zero_floats = (size_t)M * DIN + (size_t)M + (size_t)N * DIN;
  hipMemsetAsync(d_ws, 0, zero_floats * sizeof(float), stream);

  const int T = 256;
  long long pair_threads = (long long)E * 64;
  int pair_blocks = (int)((pair_threads + T - 1) / T);

  k_scatter_ve<<<pair_blocks, T, 0, stream>>>(X, vertex, edges, sums, counts, E);

  int scale_blocks = (M * DIN + T - 1) / T;
  k_edge_scale<<<scale_blocks, T, 0, stream>>>(sums, counts, dege, M);

  k_scatter_ev<<<pair_blocks, T, 0, stream>>>(sums, vertex, edges, xv, E);

  int final_blocks = (N * 64 + T - 1) / T;
  k_final<<<final_blocks, T, 0, stream>>>(xv, degv, W, b, out, N);
}

// Round 2
// 633.659 us; speedup vs baseline: 1.0949x; 1.0949x over previous
//
#include <hip/hip_runtime.h>

// UniGCNConv2 via on-device CSR (counting sort), gather-based segment sums.
// N=100000, M=200000, E=1e6, D_IN=64, out 128.

#define DIN 64
#define DOUT 128

// ---- counting-sort infrastructure ----

__global__ __launch_bounds__(256) void k_hist(
    const int* __restrict__ vertex, const int* __restrict__ edges,
    int* __restrict__ cntE, int* __restrict__ cntV, int E) {
  int i = blockIdx.x * 256 + threadIdx.x;
  if (i >= E) return;
  atomicAdd(&cntE[edges[i]], 1);
  atomicAdd(&cntV[vertex[i]], 1);
}

// per-1024-chunk reduce -> bsum[block]
__global__ __launch_bounds__(256) void k_reduce(
    const int* __restrict__ in, int* __restrict__ bsum, int n) {
  int base = blockIdx.x * 1024;
  int s = 0;
  for (int i = threadIdx.x; i < 1024; i += 256) {
    int idx = base + i;
    if (idx < n) s += in[idx];
  }
  #pragma unroll
  for (int o = 32; o > 0; o >>= 1) s += __shfl_xor(s, o);
  __shared__ int wsum[4];
  int wid = threadIdx.x >> 6, lane = threadIdx.x & 63;
  if (lane == 0) wsum[wid] = s;
  __syncthreads();
  if (threadIdx.x == 0) bsum[blockIdx.x] = wsum[0] + wsum[1] + wsum[2] + wsum[3];
}

// exclusive scan of 1024 items per block, IN PLACE (each index read+written by
// the same thread), adding boff[blockIdx.x] if boff != nullptr.
__global__ __launch_bounds__(256) void k_scan(
    int* __restrict__ data, const int* __restrict__ boff, int n) {
  __shared__ int wsum[4];
  int base = blockIdx.x * 1024 + threadIdx.x * 4;
  int a0 = (base + 0 < n) ? data[base + 0] : 0;
  int a1 = (base + 1 < n) ? data[base + 1] : 0;
  int a2 = (base + 2 < n) ? data[base + 2] : 0;
  int a3 = (base + 3 < n) ? data[base + 3] : 0;
  int tsum = a0 + a1 + a2 + a3;
  int lane = threadIdx.x & 63;
  int inc = tsum;
  #pragma unroll
  for (int o = 1; o < 64; o <<= 1) {
    int t = __shfl_up(inc, o);
    if (lane >= o) inc += t;
  }
  int wid = threadIdx.x >> 6;
  if (lane == 63) wsum[wid] = inc;
  __syncthreads();
  int woff = 0;
  for (int w = 0; w < wid; ++w) woff += wsum[w];
  int excl = woff + (inc - tsum);
  if (boff) excl += boff[blockIdx.x];
  if (base + 0 < n) data[base + 0] = excl;
  if (base + 1 < n) data[base + 1] = excl + a0;
  if (base + 2 < n) data[base + 2] = excl + a0 + a1;
  if (base + 3 < n) data[base + 3] = excl + a0 + a1 + a2;
}

// scatter payloads into CSR order. Uses off arrays as cursors; afterwards
// off[k] = end(segment k), start(k) = k ? off[k-1] : 0.
__global__ __launch_bounds__(256) void k_fill(
    const int* __restrict__ vertex, const int* __restrict__ edges,
    int* __restrict__ offE, int* __restrict__ offV,
    int* __restrict__ permE, int* __restrict__ permV, int E) {
  int i = blockIdx.x * 256 + threadIdx.x;
  if (i >= E) return;
  int v = vertex[i], e = edges[i];
  int pE = atomicAdd(&offE[e], 1);
  permE[pE] = v;                 // edge pass needs the vertex id
  int pV = atomicAdd(&offV[v], 1);
  permV[pV] = e;                 // node pass needs the edge id
}

// ---- compute passes ----

// one wave per hyperedge: Xe[e] = (sum_v X[v]) * dege[e] / max(count,1)
__global__ __launch_bounds__(256) void k_edge(
    const float* __restrict__ X, const int* __restrict__ offE,
    const int* __restrict__ permE, const float* __restrict__ dege,
    float* __restrict__ Xe, int M) {
  long long gid = (long long)blockIdx.x * 256 + threadIdx.x;
  int e = (int)(gid >> 6), lane = (int)(gid & 63);
  if (e >= M) return;
  int start = e ? offE[e - 1] : 0;
  int end = offE[e];
  float acc = 0.0f;
  for (int j = start; j < end; ++j) {
    int v = permE[j];
    acc += X[(size_t)v * DIN + lane];
  }
  float c = (float)(end - start);
  Xe[(size_t)e * DIN + lane] = acc * dege[e] / fmaxf(c, 1.0f);
}

// one wave per node: Xv = sum_e Xe[e]; *degv; L2 normalize; @W + b
__global__ __launch_bounds__(256) void k_node(
    const float* __restrict__ Xe, const int* __restrict__ offV,
    const int* __restrict__ permV, const float* __restrict__ degv,
    const float* __restrict__ W, const float* __restrict__ b,
    float* __restrict__ out, int N) {
  __shared__ float Ws[DIN * DOUT];  // 32 KB
  for (int i = threadIdx.x; i < DIN * DOUT; i += 256) Ws[i] = W[i];
  __syncthreads();

  long long gid = (long long)blockIdx.x * 256 + threadIdx.x;
  int node = (int)(gid >> 6), lane = (int)(gid & 63);
  if (node >= N) return;

  int start = node ? offV[node - 1] : 0;
  int end = offV[node];
  float acc = 0.0f;
  for (int j = start; j < end; ++j) {
    int e = permV[j];
    acc += Xe[(size_t)e * DIN + lane];
  }
  float x = acc * degv[node];

  float ss = x * x;
  #pragma unroll
  for (int o = 32; o > 0; o >>= 1) ss += __shfl_xor(ss, o);
  float scale = ss > 0.0f ? 1.0f / sqrtf(ss) : 0.0f;
  float xn = x * scale;

  float acc0 = b[lane];
  float acc1 = b[lane + 64];
  #pragma unroll
  for (int k = 0; k < DIN; ++k) {
    float xk = __shfl(xn, k);
    acc0 += xk * Ws[k * DOUT + lane];
    acc1 += xk * Ws[k * DOUT + 64 + lane];
  }
  out[(size_t)node * DOUT + lane] = acc0;
  out[(size_t)node * DOUT + 64 + lane] = acc1;
}

extern "C" void kernel_launch(void* const* d_in, const int* in_sizes, int n_in,
                              void* d_out, int out_size, void* d_ws, size_t ws_size,
                              hipStream_t stream) {
  const float* X      = (const float*)d_in[0];
  const int*   vertex = (const int*)d_in[1];
  const int*   edges  = (const int*)d_in[2];
  const float* dege   = (const float*)d_in[3];
  const float* degv   = (const float*)d_in[4];
  const float* W      = (const float*)d_in[5];
  const float* b      = (const float*)d_in[6];
  float* out = (float*)d_out;

  int N = in_sizes[0] / DIN;   // 100000
  int E = in_sizes[1];         // 1000000
  int M = in_sizes[3];         // 200000

  // workspace layout
  float* Xe   = (float*)d_ws;                       // M*64 f32
  int* offE   = (int*)(Xe + (size_t)M * DIN);       // M
  int* offV   = offE + M;                           // N
  int* permE  = offV + N;                           // E
  int* permV  = permE + E;                          // E
  int* bsumE  = permV + E;                          // <=1024
  int* bsumV  = bsumE + 1024;                       // <=1024

  // zero the histogram region (offE|offV contiguous)
  hipMemsetAsync(offE, 0, (size_t)(M + N) * sizeof(int), stream);

  const int T = 256;
  int eBlocks = (E + T - 1) / T;
  int nbE = (M + 1023) / 1024;
  int nbV = (N + 1023) / 1024;

  k_hist<<<eBlocks, T, 0, stream>>>(vertex, edges, offE, offV, E);

  k_reduce<<<nbE, T, 0, stream>>>(offE, bsumE, M);
  k_reduce<<<nbV, T, 0, stream>>>(offV, bsumV, N);
  k_scan<<<1, T, 0, stream>>>(bsumE, nullptr, nbE);
  k_scan<<<1, T, 0, stream>>>(bsumV, nullptr, nbV);
  k_scan<<<nbE, T, 0, stream>>>(offE, bsumE, M);
  k_scan<<<nbV, T, 0, stream>>>(offV, bsumV, N);

  k_fill<<<eBlocks, T, 0, stream>>>(vertex, edges, offE, offV, permE, permV, E);

  long long eWaveThreads = (long long)M * 64;
  int edgeBlocks = (int)((eWaveThreads + T - 1) / T);
  k_edge<<<edgeBlocks, T, 0, stream>>>(X, offE, permE, dege, Xe, M);

  long long nWaveThreads = (long long)N * 64;
  int nodeBlocks = (int)((nWaveThreads + T - 1) / T);
  k_node<<<nodeBlocks, T, 0, stream>>>(Xe, offV, permV, degv, W, b, out, N);
}

// Round 3
// 470.009 us; speedup vs baseline: 1.4761x; 1.3482x over previous
//
#include <hip/hip_runtime.h>

// UniGCNConv2 via on-device CSR (counting sort, combined edge+vertex table),
// gather-based segment sums with float4 rows + 4-way j-split per wave.
// N=100000, M=200000, E=1e6, D_IN=64, out 128.

#define DIN 64
#define DOUT 128

// ---- counting sort over combined table: slots [0,M) = edges, [M,M+N) = vertex ----

__global__ __launch_bounds__(256) void k_hist(
    const int* __restrict__ vertex, const int* __restrict__ edges,
    int* __restrict__ cnt, int E, int M) {
  int i = blockIdx.x * 256 + threadIdx.x;
  if (i >= E) return;
  atomicAdd(&cnt[edges[i]], 1);
  atomicAdd(&cnt[M + vertex[i]], 1);
}

__global__ __launch_bounds__(256) void k_reduce(
    const int* __restrict__ in, int* __restrict__ bsum, int n) {
  int base = blockIdx.x * 1024;
  int s = 0;
  for (int i = threadIdx.x; i < 1024; i += 256) {
    int idx = base + i;
    if (idx < n) s += in[idx];
  }
  #pragma unroll
  for (int o = 32; o > 0; o >>= 1) s += __shfl_xor(s, o);
  __shared__ int wsum[4];
  int wid = threadIdx.x >> 6, lane = threadIdx.x & 63;
  if (lane == 0) wsum[wid] = s;
  __syncthreads();
  if (threadIdx.x == 0) bsum[blockIdx.x] = wsum[0] + wsum[1] + wsum[2] + wsum[3];
}

// exclusive scan, 1024 items/block, in place; adds boff[blockIdx.x] if given.
__global__ __launch_bounds__(256) void k_scan(
    int* __restrict__ data, const int* __restrict__ boff, int n) {
  __shared__ int wsum[4];
  int base = blockIdx.x * 1024 + threadIdx.x * 4;
  int a0 = (base + 0 < n) ? data[base + 0] : 0;
  int a1 = (base + 1 < n) ? data[base + 1] : 0;
  int a2 = (base + 2 < n) ? data[base + 2] : 0;
  int a3 = (base + 3 < n) ? data[base + 3] : 0;
  int tsum = a0 + a1 + a2 + a3;
  int lane = threadIdx.x & 63;
  int inc = tsum;
  #pragma unroll
  for (int o = 1; o < 64; o <<= 1) {
    int t = __shfl_up(inc, o);
    if (lane >= o) inc += t;
  }
  int wid = threadIdx.x >> 6;
  if (lane == 63) wsum[wid] = inc;
  __syncthreads();
  int woff = 0;
  for (int w = 0; w < wid; ++w) woff += wsum[w];
  int excl = woff + (inc - tsum);
  if (boff) excl += boff[blockIdx.x];
  if (base + 0 < n) data[base + 0] = excl;
  if (base + 1 < n) data[base + 1] = excl + a0;
  if (base + 2 < n) data[base + 2] = excl + a0 + a1;
  if (base + 3 < n) data[base + 3] = excl + a0 + a1 + a2;
}

// off used as cursors; perm[0..E) gets vertex ids (edge segments),
// perm[E..2E) gets edge ids (vertex segments).
__global__ __launch_bounds__(256) void k_fill(
    const int* __restrict__ vertex, const int* __restrict__ edges,
    int* __restrict__ off, int* __restrict__ perm, int E, int M) {
  int i = blockIdx.x * 256 + threadIdx.x;
  if (i >= E) return;
  int v = vertex[i], e = edges[i];
  int pE = atomicAdd(&off[e], 1);
  perm[pE] = v;
  int pV = atomicAdd(&off[M + v], 1);
  perm[pV] = e;
}

// ---- compute passes ----

// one wave per hyperedge; 16-lane groups split the j range 4 ways, float4 rows.
__global__ __launch_bounds__(256) void k_edge(
    const float* __restrict__ X, const int* __restrict__ off,
    const int* __restrict__ perm, const float* __restrict__ dege,
    float* __restrict__ Xe, int M) {
  long long gid = (long long)blockIdx.x * 256 + threadIdx.x;
  int e = (int)(gid >> 6);
  if (e >= M) return;
  int lane = threadIdx.x & 63;
  int g = lane >> 4, li = lane & 15;
  int start = e ? off[e - 1] : 0;
  int end = off[e];
  const float4* X4 = (const float4*)X;
  float4 acc = make_float4(0.f, 0.f, 0.f, 0.f);
  int j = start + g;
  for (; j + 4 < end; j += 8) {
    int v0 = perm[j];
    int v1 = perm[j + 4];
    float4 a = X4[(size_t)v0 * 16 + li];
    float4 c = X4[(size_t)v1 * 16 + li];
    acc.x += a.x + c.x; acc.y += a.y + c.y;
    acc.z += a.z + c.z; acc.w += a.w + c.w;
  }
  if (j < end) {
    int v0 = perm[j];
    float4 a = X4[(size_t)v0 * 16 + li];
    acc.x += a.x; acc.y += a.y; acc.z += a.z; acc.w += a.w;
  }
  #pragma unroll
  for (int o = 16; o <= 32; o <<= 1) {
    acc.x += __shfl_xor(acc.x, o);
    acc.y += __shfl_xor(acc.y, o);
    acc.z += __shfl_xor(acc.z, o);
    acc.w += __shfl_xor(acc.w, o);
  }
  if (g == 0) {
    float c = (float)(end - start);
    float s = dege[e] / fmaxf(c, 1.0f);
    float4 r = make_float4(acc.x * s, acc.y * s, acc.z * s, acc.w * s);
    ((float4*)Xe)[(size_t)e * 16 + li] = r;
  }
}

// one wave per node (512-thr blocks for full occupancy with 32 KB LDS):
// gather Xe rows, *degv, L2 normalize, @W + b.
__global__ __launch_bounds__(512) void k_node(
    const float* __restrict__ Xe, const int* __restrict__ off,
    const int* __restrict__ perm, const float* __restrict__ degv,
    const float* __restrict__ W, const float* __restrict__ b,
    float* __restrict__ out, int N, int M) {
  __shared__ float Ws[DIN * DOUT];  // 32 KB
  for (int i = threadIdx.x; i < DIN * DOUT; i += 512) Ws[i] = W[i];
  __syncthreads();

  long long gid = (long long)blockIdx.x * 512 + threadIdx.x;
  int node = (int)(gid >> 6);
  if (node >= N) return;
  int lane = threadIdx.x & 63;
  int g = lane >> 4, li = lane & 15;

  int idx = M + node;
  int start = off[idx - 1];  // node 0 reads off[M-1] == E, the permV base
  int end = off[idx];
  const float4* Xe4 = (const float4*)Xe;
  float4 acc = make_float4(0.f, 0.f, 0.f, 0.f);
  int j = start + g;
  for (; j + 4 < end; j += 8) {
    int e0 = perm[j];
    int e1 = perm[j + 4];
    float4 a = Xe4[(size_t)e0 * 16 + li];
    float4 c = Xe4[(size_t)e1 * 16 + li];
    acc.x += a.x + c.x; acc.y += a.y + c.y;
    acc.z += a.z + c.z; acc.w += a.w + c.w;
  }
  if (j < end) {
    int e0 = perm[j];
    float4 a = Xe4[(size_t)e0 * 16 + li];
    acc.x += a.x; acc.y += a.y; acc.z += a.z; acc.w += a.w;
  }
  #pragma unroll
  for (int o = 16; o <= 32; o <<= 1) {
    acc.x += __shfl_xor(acc.x, o);
    acc.y += __shfl_xor(acc.y, o);
    acc.z += __shfl_xor(acc.z, o);
    acc.w += __shfl_xor(acc.w, o);
  }

  float dv = degv[node];
  acc.x *= dv; acc.y *= dv; acc.z *= dv; acc.w *= dv;

  float ss = acc.x * acc.x + acc.y * acc.y + acc.z * acc.z + acc.w * acc.w;
  #pragma unroll
  for (int o = 1; o <= 8; o <<= 1) ss += __shfl_xor(ss, o);
  float scale = ss > 0.0f ? 1.0f / sqrtf(ss) : 0.0f;
  acc.x *= scale; acc.y *= scale; acc.z *= scale; acc.w *= scale;

  // out[node] = xn @ W + b ; lane covers output cols 2*lane, 2*lane+1
  const float2* b2 = (const float2*)b;
  float2 accO = b2[lane];
  #pragma unroll
  for (int kk = 0; kk < 16; ++kk) {
    float x0 = __shfl(acc.x, kk);
    float x1 = __shfl(acc.y, kk);
    float x2 = __shfl(acc.z, kk);
    float x3 = __shfl(acc.w, kk);
    const float2* Wr = (const float2*)&Ws[(4 * kk) * DOUT];
    float2 w0 = Wr[lane];
    float2 w1 = Wr[64 + lane];
    float2 w2 = Wr[128 + lane];
    float2 w3 = Wr[192 + lane];
    accO.x += x0 * w0.x + x1 * w1.x + x2 * w2.x + x3 * w3.x;
    accO.y += x0 * w0.y + x1 * w1.y + x2 * w2.y + x3 * w3.y;
  }
  ((float2*)out)[(size_t)node * 64 + lane] = accO;
}

extern "C" void kernel_launch(void* const* d_in, const int* in_sizes, int n_in,
                              void* d_out, int out_size, void* d_ws, size_t ws_size,
                              hipStream_t stream) {
  const float* X      = (const float*)d_in[0];
  const int*   vertex = (const int*)d_in[1];
  const int*   edges  = (const int*)d_in[2];
  const float* dege   = (const float*)d_in[3];
  const float* degv   = (const float*)d_in[4];
  const float* W      = (const float*)d_in[5];
  const float* b      = (const float*)d_in[6];
  float* out = (float*)d_out;

  int N = in_sizes[0] / DIN;   // 100000
  int E = in_sizes[1];         // 1000000
  int M = in_sizes[3];         // 200000
  int MN = M + N;

  // workspace layout
  float* Xe  = (float*)d_ws;                     // M*64 f32 (51.2 MB)
  int* off   = (int*)(Xe + (size_t)M * DIN);     // M+N
  int* perm  = off + MN;                         // 2E
  int* bsum  = perm + 2 * (size_t)E;             // <=1024

  hipMemsetAsync(off, 0, (size_t)MN * sizeof(int), stream);

  const int T = 256;
  int eBlocks = (E + T - 1) / T;
  int nb = (MN + 1023) / 1024;

  k_hist<<<eBlocks, T, 0, stream>>>(vertex, edges, off, E, M);
  k_reduce<<<nb, T, 0, stream>>>(off, bsum, MN);
  k_scan<<<1, T, 0, stream>>>(bsum, nullptr, nb);
  k_scan<<<nb, T, 0, stream>>>(off, bsum, MN);
  k_fill<<<eBlocks, T, 0, stream>>>(vertex, edges, off, perm, E, M);

  long long eWaveThreads = (long long)M * 64;
  int edgeBlocks = (int)((eWaveThreads + T - 1) / T);
  k_edge<<<edgeBlocks, T, 0, stream>>>(X, off, perm, dege, Xe, M);

  long long nWaveThreads = (long long)N * 64;
  int nodeBlocks = (int)((nWaveThreads + 511) / 512);
  k_node<<<nodeBlocks, 512, 0, stream>>>(Xe, off, perm, degv, W, b, out, N, M);
}

// Round 4
// 283.409 us; speedup vs baseline: 2.4479x; 1.6584x over previous
//
#include <hip/hip_runtime.h>

// UniGCNConv2 via on-device bucketed counting sort (no global atomics),
// gather-based segment sums with float4 rows + 4-way j-split per wave.
// N=100000, M=200000, E=1e6, D_IN=64, out 128.

#define DIN 64
#define DOUT 128
#define CH 2048          // pairs per chunk for P1/P2
#define BSHIFT 10        // coarse bucket = key >> 10 (fine range 1024)

// ---- P1: per-chunk coarse-bucket histogram (combined E and V tables) ----
__global__ __launch_bounds__(256) void p1_hist(
    const int* __restrict__ vertex, const int* __restrict__ edges,
    int* __restrict__ G, int E, int BKE, int BK, int NCH) {
  __shared__ int h[512];
  for (int i = threadIdx.x; i < BK; i += 256) h[i] = 0;
  __syncthreads();
  int c = blockIdx.x;
  int s = c * CH, e_ = min(E, s + CH);
  for (int i = s + threadIdx.x; i < e_; i += 256) {
    atomicAdd(&h[edges[i] >> BSHIFT], 1);
    atomicAdd(&h[BKE + (vertex[i] >> BSHIFT)], 1);
  }
  __syncthreads();
  for (int b = threadIdx.x; b < BK; b += 256) G[(size_t)b * NCH + c] = h[b];
}

// ---- P1b: exclusive scan of each bucket row across chunks; rowTot[b] = total ----
__global__ __launch_bounds__(256) void p1b_rowscan(
    int* __restrict__ G, int* __restrict__ rowTot, int NCH) {
  int b = blockIdx.x;
  int* row = G + (size_t)b * NCH;
  __shared__ int wsum[4];
  __shared__ int carry;
  if (threadIdx.x == 0) carry = 0;
  __syncthreads();
  for (int base = 0; base < NCH; base += 256) {
    int i = base + threadIdx.x;
    int v = (i < NCH) ? row[i] : 0;
    int lane = threadIdx.x & 63, wid = threadIdx.x >> 6;
    int inc = v;
    #pragma unroll
    for (int o = 1; o < 64; o <<= 1) {
      int t = __shfl_up(inc, o);
      if (lane >= o) inc += t;
    }
    if (lane == 63) wsum[wid] = inc;
    __syncthreads();
    int woff = carry;
    for (int w = 0; w < wid; ++w) woff += wsum[w];
    int excl = woff + inc - v;
    if (i < NCH) row[i] = excl;
    __syncthreads();
    if (threadIdx.x == 0) carry += wsum[0] + wsum[1] + wsum[2] + wsum[3];
    __syncthreads();
  }
  if (threadIdx.x == 0) rowTot[b] = carry;
}

// ---- P1c: exclusive scan of bucket totals -> absolute bucket bases (+ sentinel) ----
__global__ void p1c_scan(const int* __restrict__ rowTot,
                         int* __restrict__ bucketBase, int BK) {
  if (threadIdx.x == 0 && blockIdx.x == 0) {
    int s = 0;
    for (int b = 0; b < BK; ++b) { bucketBase[b] = s; s += rowTot[b]; }
    bucketBase[BK] = s;
  }
}

// ---- P2: scatter (key,payload) pairs into bucket-partitioned temp via LDS cursors ----
__global__ __launch_bounds__(256) void p2_scatter(
    const int* __restrict__ vertex, const int* __restrict__ edges,
    const int* __restrict__ G, const int* __restrict__ bucketBase,
    uint2* __restrict__ temp, int E, int BKE, int BK, int NCH) {
  __shared__ int curs[512];
  int c = blockIdx.x;
  for (int b = threadIdx.x; b < BK; b += 256)
    curs[b] = bucketBase[b] + G[(size_t)b * NCH + c];
  __syncthreads();
  int s = c * CH, e_ = min(E, s + CH);
  for (int i = s + threadIdx.x; i < e_; i += 256) {
    int e = edges[i], v = vertex[i];
    int pE = atomicAdd(&curs[e >> BSHIFT], 1);
    temp[pE] = make_uint2((unsigned)e, (unsigned)v);
    int pV = atomicAdd(&curs[BKE + (v >> BSHIFT)], 1);
    temp[pV] = make_uint2((unsigned)v, (unsigned)e);
  }
}

// ---- P3: per-bucket fine counting sort; writes off[] (inclusive ends) and perm ----
__global__ __launch_bounds__(256) void p3_sort(
    const uint2* __restrict__ temp, const int* __restrict__ bucketBase,
    int* __restrict__ off, int* __restrict__ perm, int BKE, int M, int N) {
  __shared__ int hist[1024];
  __shared__ int pos[1024];
  __shared__ int wsum[4];
  int g = blockIdx.x;
  bool isE = g < BKE;
  int gg = isE ? g : g - BKE;
  int keyBase = gg << BSHIFT;
  int cap = isE ? M : N;
  int offBase = (isE ? 0 : M) + keyBase;
  int fineCount = min(1024, cap - keyBase);
  int pairBase = bucketBase[g], pairEnd = bucketBase[g + 1];
  int cnt = pairEnd - pairBase;

  for (int i = threadIdx.x; i < 1024; i += 256) hist[i] = 0;
  __syncthreads();
  for (int i = threadIdx.x; i < cnt; i += 256)
    atomicAdd(&hist[(int)temp[pairBase + i].x - keyBase], 1);
  __syncthreads();

  // block exclusive scan of hist[0..1024) -> pos
  int t4 = threadIdx.x * 4;
  int a0 = hist[t4], a1 = hist[t4 + 1], a2 = hist[t4 + 2], a3 = hist[t4 + 3];
  int tsum = a0 + a1 + a2 + a3;
  int lane = threadIdx.x & 63, wid = threadIdx.x >> 6;
  int inc = tsum;
  #pragma unroll
  for (int o = 1; o < 64; o <<= 1) {
    int t = __shfl_up(inc, o);
    if (lane >= o) inc += t;
  }
  if (lane == 63) wsum[wid] = inc;
  __syncthreads();
  int woff = 0;
  for (int w = 0; w < wid; ++w) woff += wsum[w];
  int excl = woff + inc - tsum;
  pos[t4] = excl; pos[t4 + 1] = excl + a0;
  pos[t4 + 2] = excl + a0 + a1; pos[t4 + 3] = excl + a0 + a1 + a2;
  __syncthreads();

  // off[key] = absolute inclusive end of segment
  for (int f = threadIdx.x; f < fineCount; f += 256)
    off[offBase + f] = pairBase + pos[f] + hist[f];
  // pos -> absolute cursors (same thread owns same f: no race with loop above)
  for (int f = threadIdx.x; f < 1024; f += 256) pos[f] += pairBase;
  __syncthreads();

  for (int i = threadIdx.x; i < cnt; i += 256) {
    uint2 p = temp[pairBase + i];
    int q = atomicAdd(&pos[(int)p.x - keyBase], 1);
    perm[q] = (int)p.y;
  }
}

// ---- compute passes (unchanged from round 3) ----

__global__ __launch_bounds__(256) void k_edge(
    const float* __restrict__ X, const int* __restrict__ off,
    const int* __restrict__ perm, const float* __restrict__ dege,
    float* __restrict__ Xe, int M) {
  long long gid = (long long)blockIdx.x * 256 + threadIdx.x;
  int e = (int)(gid >> 6);
  if (e >= M) return;
  int lane = threadIdx.x & 63;
  int g = lane >> 4, li = lane & 15;
  int start = e ? off[e - 1] : 0;
  int end = off[e];
  const float4* X4 = (const float4*)X;
  float4 acc = make_float4(0.f, 0.f, 0.f, 0.f);
  int j = start + g;
  for (; j + 4 < end; j += 8) {
    int v0 = perm[j];
    int v1 = perm[j + 4];
    float4 a = X4[(size_t)v0 * 16 + li];
    float4 c = X4[(size_t)v1 * 16 + li];
    acc.x += a.x + c.x; acc.y += a.y + c.y;
    acc.z += a.z + c.z; acc.w += a.w + c.w;
  }
  if (j < end) {
    int v0 = perm[j];
    float4 a = X4[(size_t)v0 * 16 + li];
    acc.x += a.x; acc.y += a.y; acc.z += a.z; acc.w += a.w;
  }
  #pragma unroll
  for (int o = 16; o <= 32; o <<= 1) {
    acc.x += __shfl_xor(acc.x, o);
    acc.y += __shfl_xor(acc.y, o);
    acc.z += __shfl_xor(acc.z, o);
    acc.w += __shfl_xor(acc.w, o);
  }
  if (g == 0) {
    float c = (float)(end - start);
    float s = dege[e] / fmaxf(c, 1.0f);
    float4 r = make_float4(acc.x * s, acc.y * s, acc.z * s, acc.w * s);
    ((float4*)Xe)[(size_t)e * 16 + li] = r;
  }
}

__global__ __launch_bounds__(512) void k_node(
    const float* __restrict__ Xe, const int* __restrict__ off,
    const int* __restrict__ perm, const float* __restrict__ degv,
    const float* __restrict__ W, const float* __restrict__ b,
    float* __restrict__ out, int N, int M) {
  __shared__ float Ws[DIN * DOUT];  // 32 KB
  for (int i = threadIdx.x; i < DIN * DOUT; i += 512) Ws[i] = W[i];
  __syncthreads();

  long long gid = (long long)blockIdx.x * 512 + threadIdx.x;
  int node = (int)(gid >> 6);
  if (node >= N) return;
  int lane = threadIdx.x & 63;
  int g = lane >> 4, li = lane & 15;

  int idx = M + node;
  int start = off[idx - 1];
  int end = off[idx];
  const float4* Xe4 = (const float4*)Xe;
  float4 acc = make_float4(0.f, 0.f, 0.f, 0.f);
  int j = start + g;
  for (; j + 4 < end; j += 8) {
    int e0 = perm[j];
    int e1 = perm[j + 4];
    float4 a = Xe4[(size_t)e0 * 16 + li];
    float4 c = Xe4[(size_t)e1 * 16 + li];
    acc.x += a.x + c.x; acc.y += a.y + c.y;
    acc.z += a.z + c.z; acc.w += a.w + c.w;
  }
  if (j < end) {
    int e0 = perm[j];
    float4 a = Xe4[(size_t)e0 * 16 + li];
    acc.x += a.x; acc.y += a.y; acc.z += a.z; acc.w += a.w;
  }
  #pragma unroll
  for (int o = 16; o <= 32; o <<= 1) {
    acc.x += __shfl_xor(acc.x, o);
    acc.y += __shfl_xor(acc.y, o);
    acc.z += __shfl_xor(acc.z, o);
    acc.w += __shfl_xor(acc.w, o);
  }

  float dv = degv[node];
  acc.x *= dv; acc.y *= dv; acc.z *= dv; acc.w *= dv;

  float ss = acc.x * acc.x + acc.y * acc.y + acc.z * acc.z + acc.w * acc.w;
  #pragma unroll
  for (int o = 1; o <= 8; o <<= 1) ss += __shfl_xor(ss, o);
  float scale = ss > 0.0f ? 1.0f / sqrtf(ss) : 0.0f;
  acc.x *= scale; acc.y *= scale; acc.z *= scale; acc.w *= scale;

  const float2* b2 = (const float2*)b;
  float2 accO = b2[lane];
  #pragma unroll
  for (int kk = 0; kk < 16; ++kk) {
    float x0 = __shfl(acc.x, kk);
    float x1 = __shfl(acc.y, kk);
    float x2 = __shfl(acc.z, kk);
    float x3 = __shfl(acc.w, kk);
    const float2* Wr = (const float2*)&Ws[(4 * kk) * DOUT];
    float2 w0 = Wr[lane];
    float2 w1 = Wr[64 + lane];
    float2 w2 = Wr[128 + lane];
    float2 w3 = Wr[192 + lane];
    accO.x += x0 * w0.x + x1 * w1.x + x2 * w2.x + x3 * w3.x;
    accO.y += x0 * w0.y + x1 * w1.y + x2 * w2.y + x3 * w3.y;
  }
  ((float2*)out)[(size_t)node * 64 + lane] = accO;
}

extern "C" void kernel_launch(void* const* d_in, const int* in_sizes, int n_in,
                              void* d_out, int out_size, void* d_ws, size_t ws_size,
                              hipStream_t stream) {
  const float* X      = (const float*)d_in[0];
  const int*   vertex = (const int*)d_in[1];
  const int*   edges  = (const int*)d_in[2];
  const float* dege   = (const float*)d_in[3];
  const float* degv   = (const float*)d_in[4];
  const float* W      = (const float*)d_in[5];
  const float* b      = (const float*)d_in[6];
  float* out = (float*)d_out;

  int N = in_sizes[0] / DIN;   // 100000
  int E = in_sizes[1];         // 1000000
  int M = in_sizes[3];         // 200000

  int NCH = (E + CH - 1) / CH;           // 489
  int BKE = (M + 1023) >> BSHIFT;        // 196
  int BKV = (N + 1023) >> BSHIFT;        // 98
  int BK  = BKE + BKV;                   // 294

  // workspace layout (all 8B-aligned)
  float* Xe       = (float*)d_ws;                          // M*64 f32 (51.2 MB)
  int*   off      = (int*)(Xe + (size_t)M * DIN);          // M+N
  int*   perm     = off + (M + N);                         // 2E
  uint2* temp     = (uint2*)(perm + 2 * (size_t)E);        // 2E uint2 (16 MB)
  int*   G        = (int*)(temp + 2 * (size_t)E);          // BK*NCH
  int*   rowTot   = G + (size_t)BK * NCH;                  // BK
  int*   bucketBase = rowTot + BK;                         // BK+1

  p1_hist<<<NCH, 256, 0, stream>>>(vertex, edges, G, E, BKE, BK, NCH);
  p1b_rowscan<<<BK, 256, 0, stream>>>(G, rowTot, NCH);
  p1c_scan<<<1, 64, 0, stream>>>(rowTot, bucketBase, BK);
  p2_scatter<<<NCH, 256, 0, stream>>>(vertex, edges, G, bucketBase, temp, E, BKE, BK, NCH);
  p3_sort<<<BK, 256, 0, stream>>>(temp, bucketBase, off, perm, BKE, M, N);

  long long eWaveThreads = (long long)M * 64;
  int edgeBlocks = (int)((eWaveThreads + 255) / 256);
  k_edge<<<edgeBlocks, 256, 0, stream>>>(X, off, perm, dege, Xe, M);

  long long nWaveThreads = (long long)N * 64;
  int nodeBlocks = (int)((nWaveThreads + 511) / 512);
  k_node<<<nodeBlocks, 512, 0, stream>>>(Xe, off, perm, degv, W, b, out, N, M);
}

// Round 5
// 281.188 us; speedup vs baseline: 2.4673x; 1.0079x over previous
//
#include <hip/hip_runtime.h>

// UniGCNConv2 via on-device bucketed counting sort (no global atomics),
// gather-based segment sums with float4 rows + 4-way j-split per wave.
// N=100000, M=200000, E=1e6, D_IN=64, out 128.

#define DIN 64
#define DOUT 128
#define CH 2048          // pairs per chunk for P1/P2
#define BSHIFT 10        // coarse bucket = key >> 10 (fine range 1024)

// ---- P1: per-chunk coarse-bucket histogram (combined E and V tables) ----
__global__ __launch_bounds__(256) void p1_hist(
    const int* __restrict__ vertex, const int* __restrict__ edges,
    int* __restrict__ G, int E, int BKE, int BK, int NCH) {
  __shared__ int h[512];
  for (int i = threadIdx.x; i < BK; i += 256) h[i] = 0;
  __syncthreads();
  int c = blockIdx.x;
  int s = c * CH, e_ = min(E, s + CH);
  for (int i = s + threadIdx.x; i < e_; i += 256) {
    atomicAdd(&h[edges[i] >> BSHIFT], 1);
    atomicAdd(&h[BKE + (vertex[i] >> BSHIFT)], 1);
  }
  __syncthreads();
  for (int b = threadIdx.x; b < BK; b += 256) G[(size_t)b * NCH + c] = h[b];
}

// ---- P1b: exclusive scan of each bucket row across chunks; rowTot[b] = total ----
__global__ __launch_bounds__(256) void p1b_rowscan(
    int* __restrict__ G, int* __restrict__ rowTot, int NCH) {
  int b = blockIdx.x;
  int* row = G + (size_t)b * NCH;
  __shared__ int wsum[4];
  __shared__ int carry;
  if (threadIdx.x == 0) carry = 0;
  __syncthreads();
  for (int base = 0; base < NCH; base += 256) {
    int i = base + threadIdx.x;
    int v = (i < NCH) ? row[i] : 0;
    int lane = threadIdx.x & 63, wid = threadIdx.x >> 6;
    int inc = v;
    #pragma unroll
    for (int o = 1; o < 64; o <<= 1) {
      int t = __shfl_up(inc, o);
      if (lane >= o) inc += t;
    }
    if (lane == 63) wsum[wid] = inc;
    __syncthreads();
    int woff = carry;
    for (int w = 0; w < wid; ++w) woff += wsum[w];
    int excl = woff + inc - v;
    if (i < NCH) row[i] = excl;
    __syncthreads();
    if (threadIdx.x == 0) carry += wsum[0] + wsum[1] + wsum[2] + wsum[3];
    __syncthreads();
  }
  if (threadIdx.x == 0) rowTot[b] = carry;
}

// ---- P1c: exclusive scan of bucket totals -> absolute bucket bases (+ sentinel) ----
__global__ void p1c_scan(const int* __restrict__ rowTot,
                         int* __restrict__ bucketBase, int BK) {
  if (threadIdx.x == 0 && blockIdx.x == 0) {
    int s = 0;
    for (int b = 0; b < BK; ++b) { bucketBase[b] = s; s += rowTot[b]; }
    bucketBase[BK] = s;
  }
}

// ---- P2: scatter (key,payload) pairs into bucket-partitioned temp via LDS cursors ----
__global__ __launch_bounds__(256) void p2_scatter(
    const int* __restrict__ vertex, const int* __restrict__ edges,
    const int* __restrict__ G, const int* __restrict__ bucketBase,
    uint2* __restrict__ temp, int E, int BKE, int BK, int NCH) {
  __shared__ int curs[512];
  int c = blockIdx.x;
  for (int b = threadIdx.x; b < BK; b += 256)
    curs[b] = bucketBase[b] + G[(size_t)b * NCH + c];
  __syncthreads();
  int s = c * CH, e_ = min(E, s + CH);
  for (int i = s + threadIdx.x; i < e_; i += 256) {
    int e = edges[i], v = vertex[i];
    int pE = atomicAdd(&curs[e >> BSHIFT], 1);
    temp[pE] = make_uint2((unsigned)e, (unsigned)v);
    int pV = atomicAdd(&curs[BKE + (v >> BSHIFT)], 1);
    temp[pV] = make_uint2((unsigned)v, (unsigned)e);
  }
}

// ---- P3: per-bucket fine counting sort; writes off[] (inclusive ends) and perm ----
__global__ __launch_bounds__(256) void p3_sort(
    const uint2* __restrict__ temp, const int* __restrict__ bucketBase,
    int* __restrict__ off, int* __restrict__ perm, int BKE, int M, int N) {
  __shared__ int hist[1024];
  __shared__ int pos[1024];
  __shared__ int wsum[4];
  int g = blockIdx.x;
  bool isE = g < BKE;
  int gg = isE ? g : g - BKE;
  int keyBase = gg << BSHIFT;
  int cap = isE ? M : N;
  int offBase = (isE ? 0 : M) + keyBase;
  int fineCount = min(1024, cap - keyBase);
  int pairBase = bucketBase[g], pairEnd = bucketBase[g + 1];
  int cnt = pairEnd - pairBase;

  for (int i = threadIdx.x; i < 1024; i += 256) hist[i] = 0;
  __syncthreads();
  for (int i = threadIdx.x; i < cnt; i += 256)
    atomicAdd(&hist[(int)temp[pairBase + i].x - keyBase], 1);
  __syncthreads();

  // block exclusive scan of hist[0..1024) -> pos
  int t4 = threadIdx.x * 4;
  int a0 = hist[t4], a1 = hist[t4 + 1], a2 = hist[t4 + 2], a3 = hist[t4 + 3];
  int tsum = a0 + a1 + a2 + a3;
  int lane = threadIdx.x & 63, wid = threadIdx.x >> 6;
  int inc = tsum;
  #pragma unroll
  for (int o = 1; o < 64; o <<= 1) {
    int t = __shfl_up(inc, o);
    if (lane >= o) inc += t;
  }
  if (lane == 63) wsum[wid] = inc;
  __syncthreads();
  int woff = 0;
  for (int w = 0; w < wid; ++w) woff += wsum[w];
  int excl = woff + inc - tsum;
  pos[t4] = excl; pos[t4 + 1] = excl + a0;
  pos[t4 + 2] = excl + a0 + a1; pos[t4 + 3] = excl + a0 + a1 + a2;
  __syncthreads();

  // off[key] = absolute inclusive end of segment
  for (int f = threadIdx.x; f < fineCount; f += 256)
    off[offBase + f] = pairBase + pos[f] + hist[f];
  // pos -> absolute cursors (same thread owns same f: no race with loop above)
  for (int f = threadIdx.x; f < 1024; f += 256) pos[f] += pairBase;
  __syncthreads();

  for (int i = threadIdx.x; i < cnt; i += 256) {
    uint2 p = temp[pairBase + i];
    int q = atomicAdd(&pos[(int)p.x - keyBase], 1);
    perm[q] = (int)p.y;
  }
}

// ---- compute passes (unchanged from round 3) ----

__global__ __launch_bounds__(256) void k_edge(
    const float* __restrict__ X, const int* __restrict__ off,
    const int* __restrict__ perm, const float* __restrict__ dege,
    float* __restrict__ Xe, int M) {
  long long gid = (long long)blockIdx.x * 256 + threadIdx.x;
  int e = (int)(gid >> 6);
  if (e >= M) return;
  int lane = threadIdx.x & 63;
  int g = lane >> 4, li = lane & 15;
  int start = e ? off[e - 1] : 0;
  int end = off[e];
  const float4* X4 = (const float4*)X;
  float4 acc = make_float4(0.f, 0.f, 0.f, 0.f);
  int j = start + g;
  for (; j + 4 < end; j += 8) {
    int v0 = perm[j];
    int v1 = perm[j + 4];
    float4 a = X4[(size_t)v0 * 16 + li];
    float4 c = X4[(size_t)v1 * 16 + li];
    acc.x += a.x + c.x; acc.y += a.y + c.y;
    acc.z += a.z + c.z; acc.w += a.w + c.w;
  }
  if (j < end) {
    int v0 = perm[j];
    float4 a = X4[(size_t)v0 * 16 + li];
    acc.x += a.x; acc.y += a.y; acc.z += a.z; acc.w += a.w;
  }
  #pragma unroll
  for (int o = 16; o <= 32; o <<= 1) {
    acc.x += __shfl_xor(acc.x, o);
    acc.y += __shfl_xor(acc.y, o);
    acc.z += __shfl_xor(acc.z, o);
    acc.w += __shfl_xor(acc.w, o);
  }
  if (g == 0) {
    float c = (float)(end - start);
    float s = dege[e] / fmaxf(c, 1.0f);
    float4 r = make_float4(acc.x * s, acc.y * s, acc.z * s, acc.w * s);
    ((float4*)Xe)[(size_t)e * 16 + li] = r;
  }
}

__global__ __launch_bounds__(512) void k_node(
    const float* __restrict__ Xe, const int* __restrict__ off,
    const int* __restrict__ perm, const float* __restrict__ degv,
    const float* __restrict__ W, const float* __restrict__ b,
    float* __restrict__ out, int N, int M) {
  __shared__ float Ws[DIN * DOUT];  // 32 KB
  for (int i = threadIdx.x; i < DIN * DOUT; i += 512) Ws[i] = W[i];
  __syncthreads();

  long long gid = (long long)blockIdx.x * 512 + threadIdx.x;
  int node = (int)(gid >> 6);
  if (node >= N) return;
  int lane = threadIdx.x & 63;
  int g = lane >> 4, li = lane & 15;

  int idx = M + node;
  int start = off[idx - 1];
  int end = off[idx];
  const float4* Xe4 = (const float4*)Xe;
  float4 acc = make_float4(0.f, 0.f, 0.f, 0.f);
  int j = start + g;
  for (; j + 4 < end; j += 8) {
    int e0 = perm[j];
    int e1 = perm[j + 4];
    float4 a = Xe4[(size_t)e0 * 16 + li];
    float4 c = Xe4[(size_t)e1 * 16 + li];
    acc.x += a.x + c.x; acc.y += a.y + c.y;
    acc.z += a.z + c.z; acc.w += a.w + c.w;
  }
  if (j < end) {
    int e0 = perm[j];
    float4 a = Xe4[(size_t)e0 * 16 + li];
    acc.x += a.x; acc.y += a.y; acc.z += a.z; acc.w += a.w;
  }
  #pragma unroll
  for (int o = 16; o <= 32; o <<= 1) {
    acc.x += __shfl_xor(acc.x, o);
    acc.y += __shfl_xor(acc.y, o);
    acc.z += __shfl_xor(acc.z, o);
    acc.w += __shfl_xor(acc.w, o);
  }

  float dv = degv[node];
  acc.x *= dv; acc.y *= dv; acc.z *= dv; acc.w *= dv;

  float ss = acc.x * acc.x + acc.y * acc.y + acc.z * acc.z + acc.w * acc.w;
  #pragma unroll
  for (int o = 1; o <= 8; o <<= 1) ss += __shfl_xor(ss, o);
  float scale = ss > 0.0f ? 1.0f / sqrtf(ss) : 0.0f;
  acc.x *= scale; acc.y *= scale; acc.z *= scale; acc.w *= scale;

  const float2* b2 = (const float2*)b;
  float2 accO = b2[lane];
  #pragma unroll
  for (int kk = 0; kk < 16; ++kk) {
    float x0 = __shfl(acc.x, kk);
    float x1 = __shfl(acc.y, kk);
    float x2 = __shfl(acc.z, kk);
    float x3 = __shfl(acc.w, kk);
    const float2* Wr = (const float2*)&Ws[(4 * kk) * DOUT];
    float2 w0 = Wr[lane];
    float2 w1 = Wr[64 + lane];
    float2 w2 = Wr[128 + lane];
    float2 w3 = Wr[192 + lane];
    accO.x += x0 * w0.x + x1 * w1.x + x2 * w2.x + x3 * w3.x;
    accO.y += x0 * w0.y + x1 * w1.y + x2 * w2.y + x3 * w3.y;
  }
  ((float2*)out)[(size_t)node * 64 + lane] = accO;
}

extern "C" void kernel_launch(void* const* d_in, const int* in_sizes, int n_in,
                              void* d_out, int out_size, void* d_ws, size_t ws_size,
                              hipStream_t stream) {
  const float* X      = (const float*)d_in[0];
  const int*   vertex = (const int*)d_in[1];
  const int*   edges  = (const int*)d_in[2];
  const float* dege   = (const float*)d_in[3];
  const float* degv   = (const float*)d_in[4];
  const float* W      = (const float*)d_in[5];
  const float* b      = (const float*)d_in[6];
  float* out = (float*)d_out;

  int N = in_sizes[0] / DIN;   // 100000
  int E = in_sizes[1];         // 1000000
  int M = in_sizes[3];         // 200000

  int NCH = (E + CH - 1) / CH;           // 489
  int BKE = (M + 1023) >> BSHIFT;        // 196
  int BKV = (N + 1023) >> BSHIFT;        // 98
  int BK  = BKE + BKV;                   // 294

  // workspace layout (all 8B-aligned)
  float* Xe       = (float*)d_ws;                          // M*64 f32 (51.2 MB)
  int*   off      = (int*)(Xe + (size_t)M * DIN);          // M+N
  int*   perm     = off + (M + N);                         // 2E
  uint2* temp     = (uint2*)(perm + 2 * (size_t)E);        // 2E uint2 (16 MB)
  int*   G        = (int*)(temp + 2 * (size_t)E);          // BK*NCH
  int*   rowTot   = G + (size_t)BK * NCH;                  // BK
  int*   bucketBase = rowTot + BK;                         // BK+1

  p1_hist<<<NCH, 256, 0, stream>>>(vertex, edges, G, E, BKE, BK, NCH);
  p1b_rowscan<<<BK, 256, 0, stream>>>(G, rowTot, NCH);
  p1c_scan<<<1, 64, 0, stream>>>(rowTot, bucketBase, BK);
  p2_scatter<<<NCH, 256, 0, stream>>>(vertex, edges, G, bucketBase, temp, E, BKE, BK, NCH);
  p3_sort<<<BK, 256, 0, stream>>>(temp, bucketBase, off, perm, BKE, M, N);

  long long eWaveThreads = (long long)M * 64;
  int edgeBlocks = (int)((eWaveThreads + 255) / 256);
  k_edge<<<edgeBlocks, 256, 0, stream>>>(X, off, perm, dege, Xe, M);

  long long nWaveThreads = (long long)N * 64;
  int nodeBlocks = (int)((nWaveThreads + 511) / 512);
  k_node<<<nodeBlocks, 512, 0, stream>>>(Xe, off, perm, degv, W, b, out, N, M);
}